// Round 6
// baseline (2324.693 us; speedup 1.0000x reference)
//
#include <hip/hip_runtime.h>
#include <stdint.h>
#include <math.h>

// DialogueSNN: B=8, S=256, V=32000, E=64, H=128, T=20 inner steps.
// All internal math in f64 to track the high-precision numpy reference
// (spike outputs are binary: one flipped threshold decision = absmax 1.0).
// R4 bench: k2 = 1543us, 723 cy/step, VALUBusy 17% -> latency-bound on the
// wave-uniform mask loads (1-deep prefetch hid only ~124 of ~600 cy).
//
// R5 change: k2 mask loads now 8-step-deep software pipeline in statically
// indexed rotating registers (32 ulonglong2 loads in flight, vmcnt-tracked
// exactly). Steady-state body has ZERO stores: spike bits accumulate in a
// per-chain u32, flushed as 32 coalesced f32 stores every 640 steps.
//
// Workspace: cur1 (256*8*128 f64 = 2 MB) + masks (5120*16 u64 = 640 KB).

#define BB 8
#define SS 256
#define EE 64
#define HH 128
#define VV 32000
#define TT 20
#define NG (SS*TT)   // 5120 total steps

#define TBV 128      // v-columns per block in k2 (LDS slice = 64 KB)
#define BSP 4        // batch chains per thread in k2
#define PD  8        // mask-load pipeline depth (steps); NG%PD==0, 640%PD==0

typedef unsigned long long u64;

__global__ __launch_bounds__(HH) void k0_cur1(
    const int* __restrict__ x, const float* __restrict__ embed,
    const float* __restrict__ W1, const float* __restrict__ b1,
    double* __restrict__ cur1)
{
    int blk = blockIdx.x;          // t*BB + b
    int t = blk >> 3, b = blk & 7;
    int h = threadIdx.x;           // 0..127
    int ix = x[b*SS + t];
    const float* erow = embed + (size_t)ix * EE;
    double acc = 0.0;
    #pragma unroll
    for (int e = 0; e < EE; ++e)
        acc += (double)erow[e] * (double)W1[e*HH + h];
    acc += (double)b1[h];
    cur1[((size_t)t*BB + b)*HH + h] = acc;
}

__global__ __launch_bounds__(64) void k1_l1(
    const double* __restrict__ cur1, u64* __restrict__ masks,
    float* __restrict__ out_mem1)
{
    // one wave per block; blockIdx.x = b*2 + half; lane = h within half
    int b = blockIdx.x >> 1, half = blockIdx.x & 1;
    int lane = threadIdx.x;
    int h = half*64 + lane;
    double m = 0.0;
    double r = 0.0;   // reset at step s == spk at step s-1; heaviside(0-1)=0 init
    for (int t = 0; t < SS; ++t) {
        double cur = cur1[((size_t)t*BB + b)*HH + h];
        #pragma unroll
        for (int s = 0; s < TT; ++s) {
            m = __builtin_fma(0.95, m, cur) - r;   // chain: fma -> sub
            bool spk = m > 1.0;
            r = spk ? 1.0 : 0.0;
            u64 msk = __ballot(spk);
            if (lane == 0) masks[(size_t)(t*TT + s)*(2*BB) + b*2 + half] = msk;
        }
    }
    out_mem1[b*HH + h] = (float)m;
}

__global__ __launch_bounds__(TBV, 1) void k2_l2(
    const float* __restrict__ W2, const float* __restrict__ b2,
    const u64* __restrict__ masks, float* __restrict__ out)
{
    __shared__ float w2s[HH][TBV];   // 64 KB, resident for all 5120 steps
    int tid = threadIdx.x;
    int v0 = blockIdx.x * TBV;
    int by = blockIdx.y;
    int b0 = by * BSP;
    for (int i = tid; i < HH*TBV; i += TBV) {
        int hh = i >> 7;             // i / TBV (TBV==128)
        w2s[hh][tid] = W2[(size_t)hh*VV + v0 + tid];
    }
    __syncthreads();

    const int v = v0 + tid;
    const double b2v = (double)b2[v];

    double mm[BSP], rr[BSP];
    unsigned int sb[BSP];            // spike bits for 32 t's, flushed batch-wise
    float* outp[BSP];
    #pragma unroll
    for (int j = 0; j < BSP; ++j) {
        mm[j] = 0.0; rr[j] = 0.0; sb[j] = 0u;
        outp[j] = out + (size_t)(b0 + j)*SS*VV + v;
    }

    // per step: 8 u64 (chains b0..b0+3, halves 0/1) = 4 ulonglong2, contiguous.
    const ulonglong2* mv = (const ulonglong2*)masks;   // 8 vectors per step
    const size_t vb = (size_t)by * BSP;                // vector offset of b0

    // prologue: fill PD-slot rotating buffer (steps 0..PD-1)
    ulonglong2 buf[PD][BSP];
    #pragma unroll
    for (int p = 0; p < PD; ++p)
        #pragma unroll
        for (int q = 0; q < BSP; ++q)
            buf[p][q] = mv[(size_t)p*8 + vb + q];

    for (int g0 = 0; g0 < NG; g0 += PD) {
        #pragma unroll
        for (int p = 0; p < PD; ++p) {
            const int g = g0 + p;                     // p static -> buf idx static
            const int t = g / TT;
            const bool emit = (g - t*TT) == (TT - 1); // last inner step of t

            bool spkb[BSP];
            #pragma unroll
            for (int j = 0; j < BSP; ++j) {
                u64 m0 = buf[p][j].x, m1 = buf[p][j].y;
                double sum = 0.0;
                while (m0) { int hh = __builtin_ctzll(m0); m0 &= (m0 - 1);
                             sum += (double)w2s[hh][tid]; }
                while (m1) { int hh = __builtin_ctzll(m1); m1 &= (m1 - 1);
                             sum += (double)w2s[64 + hh][tid]; }
                double cur = sum + b2v;                    // matches np op order
                mm[j] = __builtin_fma(0.95, mm[j], cur) - rr[j];
                bool spk = mm[j] > 1.0;
                rr[j] = spk ? 1.0 : 0.0;
                spkb[j] = spk;
            }
            if (emit) {
                const unsigned int bitp = (unsigned int)(t & 31);
                #pragma unroll
                for (int j = 0; j < BSP; ++j)
                    sb[j] |= (spkb[j] ? 1u : 0u) << bitp;
            }

            // refill this slot with step g+PD (clamped; tail reloads are inert)
            int gn = g + PD; if (gn > NG - 1) gn = NG - 1;
            #pragma unroll
            for (int q = 0; q < BSP; ++q)
                buf[p][q] = mv[(size_t)gn*8 + vb + q];
        }

        // flush 32 t's of spikes every 640 steps (group-aligned: 640%PD==0)
        if (((g0 + PD) % (32*TT)) == 0) {
            const int tf0 = ((g0 + PD) / (32*TT) - 1) * 32;
            #pragma unroll
            for (int j = 0; j < BSP; ++j) {
                #pragma unroll
                for (int k = 0; k < 32; ++k)
                    outp[j][(size_t)(tf0 + k)*VV] = (float)((sb[j] >> k) & 1u);
                sb[j] = 0u;
            }
        }
    }

    float* mem2out = out + (size_t)BB*SS*VV + (size_t)BB*HH;
    #pragma unroll
    for (int j = 0; j < BSP; ++j)
        mem2out[(size_t)(b0 + j)*VV + v] = (float)mm[j];
}

extern "C" void kernel_launch(void* const* d_in, const int* in_sizes, int n_in,
                              void* d_out, int out_size, void* d_ws, size_t ws_size,
                              hipStream_t stream)
{
    const int*   x     = (const int*)  d_in[0];
    const float* embed = (const float*)d_in[1];
    const float* W1    = (const float*)d_in[2];
    const float* b1    = (const float*)d_in[3];
    const float* W2    = (const float*)d_in[4];
    const float* b2    = (const float*)d_in[5];
    float* out = (float*)d_out;

    // workspace carve: cur1 f64 [256*8*128] then masks u64 [5120*16]
    double* cur1 = (double*)d_ws;
    u64* masks = (u64*)((char*)d_ws + (size_t)SS*BB*HH*sizeof(double));

    k0_cur1<<<SS*BB, HH, 0, stream>>>(x, embed, W1, b1, cur1);
    k1_l1<<<BB*2, 64, 0, stream>>>(cur1, masks, out + (size_t)BB*SS*VV);
    k2_l2<<<dim3(VV/TBV, BB/BSP), TBV, 0, stream>>>(W2, b2, masks, out);
}